// Round 5
// baseline (701.656 us; speedup 1.0000x reference)
//
#include <hip/hip_runtime.h>
#include <math.h>
#include <stdint.h>

#define BATCH 64
#define N 128
#define DIM 64
#define ARR_CAP 640

typedef unsigned uint32x2_t __attribute__((ext_vector_type(2)));

// branchless monotone float->uint (order-preserving incl. +-inf)
__device__ __forceinline__ unsigned monokey(float x) {
    unsigned b = __float_as_uint(x);
    return b ^ (unsigned)(((int)b >> 31) | (int)0x80000000u);
}

__device__ __forceinline__ unsigned umin_(unsigned a, unsigned b) { return a < b ? a : b; }
__device__ __forceinline__ unsigned umax_(unsigned a, unsigned b) { return a > b ? a : b; }
__device__ __forceinline__ int rfl(int v) { return __builtin_amdgcn_readfirstlane(v); }
__device__ __forceinline__ int rl_i(int v, int l) { return __builtin_amdgcn_readlane(v, l); }
__device__ __forceinline__ float rl_f(float v, int l) {
    return __int_as_float(__builtin_amdgcn_readlane(__float_as_int(v), l));
}

#define DPP_ROR(x, n) __builtin_amdgcn_update_dpp((int)(x), (int)(x), 0x120 + (n), 0xF, 0xF, false)

// full-wave min of packed keys; every lane gets the result. VALU-only.
__device__ __forceinline__ unsigned wave_kmin(unsigned k) {
    unsigned a = (unsigned)DPP_ROR(k, 1);
    unsigned b = (unsigned)DPP_ROR(k, 2);
    k = umin_(k, umin_(a, b));            // 0..2
    a = (unsigned)DPP_ROR(k, 3);
    b = (unsigned)DPP_ROR(k, 6);
    k = umin_(k, umin_(a, b));            // 0..8
    a = (unsigned)DPP_ROR(k, 9);
    k = umin_(k, a);                      // 0..15 (wrap overlap OK for min)
#if __has_builtin(__builtin_amdgcn_permlane16_swap)
    {
        uint32x2_t r = __builtin_amdgcn_permlane16_swap(k, k, false, false);
        k = umin_(r[0], r[1]);
    }
#else
    k = umin_(k, (unsigned)__shfl_xor((int)k, 16));
#endif
#if __has_builtin(__builtin_amdgcn_permlane32_swap)
    {
        uint32x2_t r = __builtin_amdgcn_permlane32_swap(k, k, false, false);
        k = umin_(r[0], r[1]);
    }
#else
    k = umin_(k, (unsigned)__shfl_xor((int)k, 32));
#endif
    return k;
}

// two smallest keys across the wave (disjoint-window rotate-reduce). ks<=kb kept.
__device__ __forceinline__ void wave_kmin2(unsigned& ks, unsigned& kb, int lane) {
    unsigned ps, pb;
#define KM2_COMBINE { unsigned ns = umin_(ks, ps); kb = umin_(umin_(kb, pb), umax_(ks, ps)); ks = ns; }
    ps = (unsigned)DPP_ROR(ks, 1); pb = (unsigned)DPP_ROR(kb, 1); KM2_COMBINE;
    ps = (unsigned)DPP_ROR(ks, 2); pb = (unsigned)DPP_ROR(kb, 2); KM2_COMBINE;
    ps = (unsigned)DPP_ROR(ks, 4); pb = (unsigned)DPP_ROR(kb, 4); KM2_COMBINE;
    ps = (unsigned)DPP_ROR(ks, 8); pb = (unsigned)DPP_ROR(kb, 8); KM2_COMBINE;
#if __has_builtin(__builtin_amdgcn_permlane16_swap)
    {
        uint32x2_t rs = __builtin_amdgcn_permlane16_swap(ks, ks, false, false);
        uint32x2_t rb = __builtin_amdgcn_permlane16_swap(kb, kb, false, false);
        ps = (lane & 16) ? rs[0] : rs[1]; pb = (lane & 16) ? rb[0] : rb[1];
    }
    KM2_COMBINE;
#else
    ps = (unsigned)__shfl_xor((int)ks, 16); pb = (unsigned)__shfl_xor((int)kb, 16); KM2_COMBINE;
#endif
#if __has_builtin(__builtin_amdgcn_permlane32_swap)
    {
        uint32x2_t rs = __builtin_amdgcn_permlane32_swap(ks, ks, false, false);
        uint32x2_t rb = __builtin_amdgcn_permlane32_swap(kb, kb, false, false);
        ps = (lane & 32) ? rs[0] : rs[1]; pb = (lane & 32) ? rb[0] : rb[1];
    }
    KM2_COMBINE;
#else
    ps = (unsigned)__shfl_xor((int)ks, 32); pb = (unsigned)__shfl_xor((int)kb, 32); KM2_COMBINE;
#endif
#undef KM2_COMBINE
}

// Key layout: [31:15] truncated monokey(value), [14:7] p (0=free col), [6] colbit, [5:0] lane.
#define PACK_KEY(val, p, colbit, lane) \
    ((monokey(val) & 0xFFFF8000u) | ((unsigned)(p) << 7) | ((unsigned)(colbit) << 6) | (unsigned)(lane))

// One block = one batch, 64 threads (1 wave). Lane owns 1-based columns ja=lane+1, jb=lane+65.
// Column state (p, u[p]) lives in the owner lane's registers; all cross-column access is
// wave-uniform readlane. dist rows are prefetched so LDS latency overlaps decode/update.
__global__ __launch_bounds__(64, 1)
void lsap_kernel(const float* __restrict__ y_true, const float* __restrict__ y_pred,
                 float* __restrict__ batch_sums, float* __restrict__ out, int use_atomic) {
    __shared__ float dist[N * N];            // 64 KB; columns ca/cb read only by owner lane
    __shared__ float ytl[N * DIM];           // 32 KB
    __shared__ int unlist[N + 8];
    __shared__ int flags[N];

    const int b = blockIdx.x;
    const int lane = threadIdx.x;
    const int ca = lane, cb = lane + 64;
    const int ja = lane + 1, jb = lane + 65;

    // ---- stage y_true[b] into LDS ----
    {
        const float4* yt4 = (const float4*)(y_true + (size_t)b * N * DIM);
        float4* ytl4 = (float4*)ytl;
        for (int k = lane; k < N * DIM / 4; k += 64) ytl4[k] = yt4[k];
    }

    // ---- y_pred rows ca, cb into registers ----
    float ypa[DIM], ypb[DIM];
    {
        const float4* pa4 = (const float4*)(y_pred + (size_t)b * N * DIM + (size_t)ca * DIM);
        const float4* pb4 = (const float4*)(y_pred + (size_t)b * N * DIM + (size_t)cb * DIM);
        #pragma unroll
        for (int k = 0; k < DIM / 4; ++k) {
            float4 v4 = pa4[k];
            ypa[4*k+0]=v4.x; ypa[4*k+1]=v4.y; ypa[4*k+2]=v4.z; ypa[4*k+3]=v4.w;
            float4 w4 = pb4[k];
            ypb[4*k+0]=w4.x; ypb[4*k+1]=w4.y; ypb[4*k+2]=w4.z; ypb[4*k+3]=w4.w;
        }
    }
    __syncthreads();   // ytl visible

    // ---- Phase A: dist columns + column minima (v init) ----
    float va = INFINITY, vb = INFINITY;      // v[ja], v[jb]
    for (int i = 0; i < N; ++i) {
        const float4* yr = (const float4*)(ytl + i * DIM);
        float a0 = 0.f, a1 = 0.f;
        #pragma unroll
        for (int k = 0; k < DIM / 4; ++k) {
            float4 t4 = yr[k];
            float d;
            d = t4.x - ypa[4*k+0]; a0 = fmaf(d, d, a0);
            d = t4.y - ypa[4*k+1]; a0 = fmaf(d, d, a0);
            d = t4.z - ypa[4*k+2]; a0 = fmaf(d, d, a0);
            d = t4.w - ypa[4*k+3]; a0 = fmaf(d, d, a0);
            d = t4.x - ypb[4*k+0]; a1 = fmaf(d, d, a1);
            d = t4.y - ypb[4*k+1]; a1 = fmaf(d, d, a1);
            d = t4.z - ypb[4*k+2]; a1 = fmaf(d, d, a1);
            d = t4.w - ypb[4*k+3]; a1 = fmaf(d, d, a1);
        }
        float d0 = sqrtf(a0), d1 = sqrtf(a1);
        dist[i * N + ca] = d0;
        dist[i * N + cb] = d1;
        va = fminf(va, d0);
        vb = fminf(vb, d1);
    }

    // Column state in registers.
    int   pa = 0, pb = 0;          // assigned row (1-based; 0=free)
    float upa = 0.f, upb = 0.f;    // u[p[j]]
    float ura = 0.f, urb = 0.f;    // u_row for rows lane / lane+64
    int   waya = 0, wayb = 0;

    // ---- Phase B: row minima (kmin2) + greedy assignment with reduction transfer ----
    int nun = 0;
    float pd0 = dist[ca], pd1 = dist[cb];   // row 0 prefetch (own columns; no barrier needed)
    for (int r = 0; r < N; ++r) {
        float c0 = pd0 - va, c1 = pd1 - vb;
        if (r + 1 < N) { pd0 = dist[(r+1) * N + ca]; pd1 = dist[(r+1) * N + cb]; }
        unsigned k0 = PACK_KEY(c0, pa, 0, lane);
        unsigned k1 = PACK_KEY(c1, pb, 1, lane);
        unsigned ks = umin_(k0, k1), kb2 = umax_(k0, k1);
        wave_kmin2(ks, kb2, lane);
        int s1 = rfl((int)ks);
        int s2 = rfl((int)kb2);
        int w1 = s1 & 63, cb1 = (s1 >> 6) & 1, pj1 = (s1 >> 7) & 0xFF;
        float u1 = rl_f(cb1 ? c1 : c0, w1);
        float u2 = rl_f(((s2 >> 6) & 1) ? c1 : c0, s2 & 63);
        int j1 = 1 + w1 + (cb1 << 6);
        if (pj1 == 0) {
            float dd = u2 - u1;              // reduction transfer
            if (ja == j1) { pa = r + 1; upa = u2; va -= dd; }
            if (jb == j1) { pb = r + 1; upb = u2; vb -= dd; }
            if ((r & 63) == lane) { if (r < 64) ura = u2; else urb = u2; }
        } else {
            unlist[nun] = r;
            ++nun;
            if ((r & 63) == lane) { if (r < 64) ura = u1; else urb = u1; }
        }
    }

    // ---- Augmenting row reduction (LAPJV): immediate reprocess of displaced rows,
    //      queue-front dist prefetched one op ahead.
    {
        int k = 0;
        int icur = -1; float d0 = 0.f, d1 = 0.f;
        int qi = -1; float qd0 = 0.f, qd1 = 0.f;
        if (nun > 0) {
            icur = rfl(unlist[0]); k = 1;
            d0 = dist[icur * N + ca]; d1 = dist[icur * N + cb];
            if (k < nun) { qi = rfl(unlist[k]); qd0 = dist[qi * N + ca]; qd1 = dist[qi * N + cb]; }
        }
        int ops = 0;
        while (icur >= 0 && ops < ARR_CAP) {
            ++ops;
            float c0 = d0 - va, c1 = d1 - vb;
            unsigned k0 = PACK_KEY(c0, pa, 0, lane);
            unsigned k1 = PACK_KEY(c1, pb, 1, lane);
            unsigned ks = umin_(k0, k1), kb2 = umax_(k0, k1);
            wave_kmin2(ks, kb2, lane);
            int s1 = rfl((int)ks);
            int s2 = rfl((int)kb2);
            int pj1 = (s1 >> 7) & 0xFF, pj2 = (s2 >> 7) & 0xFF;
            bool transfer = ((unsigned)s1 >> 15) < ((unsigned)s2 >> 15);
            int it0 = transfer ? pj1 : (pj1 ? pj2 : 0);

            // prefetch next row's dist ASAP (overlaps readlanes + updates below)
            float nd0, nd1;
            if (it0) { nd0 = dist[(it0 - 1) * N + ca]; nd1 = dist[(it0 - 1) * N + cb]; }
            else     { nd0 = qd0; nd1 = qd1; }

            int w1 = s1 & 63, cb1 = (s1 >> 6) & 1;
            int w2 = s2 & 63, cb2 = (s2 >> 6) & 1;
            float u1 = rl_f(cb1 ? c1 : c0, w1);
            float u2 = rl_f(cb2 ? c1 : c0, w2);
            int j1 = 1 + w1 + (cb1 << 6);
            int j2 = 1 + w2 + (cb2 << 6);
            int jt = transfer ? j1 : (pj1 ? j2 : j1);
            if (transfer) {
                float dd = u2 - u1;
                if (ja == j1) va -= dd;
                if (jb == j1) vb -= dd;
            }
            if (ja == jt) { pa = icur + 1; upa = u2; }
            if (jb == jt) { pb = icur + 1; upb = u2; }
            if ((icur & 63) == lane) { if (icur < 64) ura = u2; else urb = u2; }

            if (it0) { icur = it0 - 1; d0 = nd0; d1 = nd1; }
            else {
                icur = qi; d0 = nd0; d1 = nd1;
                if (icur >= 0) {
                    ++k;
                    if (k < nun) { qi = rfl(unlist[k]); qd0 = dist[qi * N + ca]; qd1 = dist[qi * N + cb]; }
                    else qi = -1;
                }
            }
        }
    }

    // ---- rebuild free-row list (ballot/popcount; order irrelevant) ----
    flags[lane] = 0; flags[lane + 64] = 0;
    if (pa) flags[pa - 1] = 1;
    if (pb) flags[pb - 1] = 1;
    int f0 = flags[lane] ^ 1;
    int f1 = flags[lane + 64] ^ 1;
    unsigned long long b0 = __ballot(f0), b1 = __ballot(f1);
    int nfree0 = __popcll(b0);
    int nfree = nfree0 + __popcll(b1);
    unsigned long long lt = (1ull << lane) - 1ull;
    if (f0) unlist[__popcll(b0 & lt)] = lane;
    if (f1) unlist[nfree0 + __popcll(b1 & lt)] = lane + 64;

    // ---- Dijkstra augmenting phases for remaining free rows ----
    for (int t = 0; t < nfree; ++t) {
        int r = rfl(unlist[t]);
        float d0 = dist[r * N + ca], d1 = dist[r * N + cb];   // issue early
        float u_i = rl_f((r >= 64) ? urb : ura, r & 63);
        float mina = INFINITY, minb = INFINITY;
        int useda = 0, usedb = 0;
        waya = 0; wayb = 0;
        float uacca = 0.f, uaccb = 0.f;
        float u_acc_i = u_i;
        float u0c = u_i;
        int j0 = 0;

        for (int it = 0; it < 2 * N; ++it) {
            if (ja == j0) useda = 1;
            if (jb == j0) usedb = 1;
            if (!useda) { float cur = d0 - u0c - va; if (cur < mina) { mina = cur; waya = j0; } }
            if (!usedb) { float cur = d1 - u0c - vb; if (cur < minb) { minb = cur; wayb = j0; } }

            float fa = useda ? INFINITY : mina;
            float fb = usedb ? INFINITY : minb;
            unsigned kA = PACK_KEY(fa, pa, 0, lane);
            unsigned kB = PACK_KEY(fb, pb, 1, lane);
            unsigned kk = wave_kmin(umin_(kA, kB));
            int s = rfl((int)kk);
            int i1 = (s >> 7) & 0xFF;

            // issue next dist-row read immediately (i1 from key bits, SALU only)
            float nd0, nd1;
            if (i1) { nd0 = dist[(i1 - 1) * N + ca]; nd1 = dist[(i1 - 1) * N + cb]; }

            int w = s & 63, cbw = (s >> 6) & 1;
            float delta = rl_f(cbw ? fb : fa, w);          // exact; overlaps LDS wait
            float u1v = rl_f(cbw ? upb : upa, w);

            if (useda) { va -= delta; uacca += delta; } else { mina -= delta; }
            if (usedb) { vb -= delta; uaccb += delta; } else { minb -= delta; }
            u_acc_i += delta;

            j0 = 1 + w + (cbw << 6);
            if (i1 == 0) break;
            u0c = u1v; d0 = nd0; d1 = nd1;
        }

        if (useda) upa += uacca;
        if (usedb) upb += uaccb;

        // ---- augment: register readlane chase (uniform) ----
        int jj = j0;
        for (int hop = 0; hop < N + 1; ++hop) {
            int wj = (jj - 1) & 63;
            int sbj = (jj > 64) ? 1 : 0;
            int jp = rl_i(sbj ? wayb : waya, wj);
            int np; float nu;
            if (jp == 0) { np = r + 1; nu = u_acc_i; }
            else {
                int wp = (jp - 1) & 63;
                int sbp = (jp > 64) ? 1 : 0;
                np = rl_i(sbp ? pb : pa, wp);
                nu = rl_f(sbp ? upb : upa, wp);
            }
            if (ja == jj) { pa = np; upa = nu; }
            if (jb == jj) { pb = np; upb = nu; }
            if (jp == 0) break;
            jj = jp;
        }
    }

    // ---- matched sum ----
    float s = dist[(pa - 1) * N + ca] + dist[(pb - 1) * N + cb];
    #pragma unroll
    for (int m = 1; m < 64; m <<= 1) s += __shfl_xor(s, m);
    if (lane == 0) {
        if (use_atomic) atomicAdd(out, s * (1.0f / (float)BATCH));
        else batch_sums[b] = s;
    }
}

__global__ __launch_bounds__(64)
void reduce_kernel(const float* __restrict__ bs, float* __restrict__ out) {
    int tid = threadIdx.x;
    float v = bs[tid];
    #pragma unroll
    for (int m = 1; m < 64; m <<= 1) v += __shfl_xor(v, m);
    if (tid == 0) out[0] = v * (1.0f / (float)BATCH);
}

extern "C" void kernel_launch(void* const* d_in, const int* in_sizes, int n_in,
                              void* d_out, int out_size, void* d_ws, size_t ws_size,
                              hipStream_t stream) {
    const float* y_true = (const float*)d_in[0];
    const float* y_pred = (const float*)d_in[1];
    float* out = (float*)d_out;

    if (ws_size >= BATCH * sizeof(float)) {
        float* bs = (float*)d_ws;
        lsap_kernel<<<BATCH, 64, 0, stream>>>(y_true, y_pred, bs, out, 0);
        reduce_kernel<<<1, 64, 0, stream>>>(bs, out);
    } else {
        hipMemsetAsync(d_out, 0, sizeof(float), stream);
        lsap_kernel<<<BATCH, 64, 0, stream>>>(y_true, y_pred, nullptr, out, 1);
    }
}

// Round 6
// 657.401 us; speedup vs baseline: 1.0673x; 1.0673x over previous
//
#include <hip/hip_runtime.h>
#include <math.h>
#include <stdint.h>

#define BATCH 64
#define N 128
#define DIM 64
#define NSCALES 4
#define JACOBI_MIN_FREE 16
#define MAX_ROUNDS 3000

typedef unsigned uint32x2_t __attribute__((ext_vector_type(2)));

// branchless monotone float->uint (order-preserving incl. +-inf)
__device__ __forceinline__ unsigned monokey(float x) {
    unsigned b = __float_as_uint(x);
    return b ^ (unsigned)(((int)b >> 31) | (int)0x80000000u);
}
__device__ __forceinline__ float monoval(unsigned k) {
    unsigned b = (k & 0x80000000u) ? (k & 0x7FFFFFFFu) : ~k;
    return __uint_as_float(b);
}

__device__ __forceinline__ unsigned umin_(unsigned a, unsigned b) { return a < b ? a : b; }
__device__ __forceinline__ unsigned umax_(unsigned a, unsigned b) { return a > b ? a : b; }
__device__ __forceinline__ int rfl(int v) { return __builtin_amdgcn_readfirstlane(v); }
__device__ __forceinline__ int rl_i(int v, int l) { return __builtin_amdgcn_readlane(v, l); }
__device__ __forceinline__ float rl_f(float v, int l) {
    return __int_as_float(__builtin_amdgcn_readlane(__float_as_int(v), l));
}

#define DPP_ROR(x, n) __builtin_amdgcn_update_dpp((int)(x), (int)(x), 0x120 + (n), 0xF, 0xF, false)

// full-wave min of packed keys; every lane gets the result. VALU-only.
__device__ __forceinline__ unsigned wave_kmin(unsigned k) {
    unsigned a = (unsigned)DPP_ROR(k, 1);
    unsigned b = (unsigned)DPP_ROR(k, 2);
    k = umin_(k, umin_(a, b));
    a = (unsigned)DPP_ROR(k, 3);
    b = (unsigned)DPP_ROR(k, 6);
    k = umin_(k, umin_(a, b));
    a = (unsigned)DPP_ROR(k, 9);
    k = umin_(k, a);                      // covers 0..15 within each 16-group
#if __has_builtin(__builtin_amdgcn_permlane16_swap)
    { uint32x2_t r = __builtin_amdgcn_permlane16_swap(k, k, false, false); k = umin_(r[0], r[1]); }
#else
    k = umin_(k, (unsigned)__shfl_xor((int)k, 16));
#endif
#if __has_builtin(__builtin_amdgcn_permlane32_swap)
    { uint32x2_t r = __builtin_amdgcn_permlane32_swap(k, k, false, false); k = umin_(r[0], r[1]); }
#else
    k = umin_(k, (unsigned)__shfl_xor((int)k, 32));
#endif
    return k;
}

// two smallest keys across the wave. ks<=kb kept.
__device__ __forceinline__ void wave_kmin2(unsigned& ks, unsigned& kb, int lane) {
    unsigned ps, pb;
#define KM2_COMBINE { unsigned ns = umin_(ks, ps); kb = umin_(umin_(kb, pb), umax_(ks, ps)); ks = ns; }
    ps = (unsigned)DPP_ROR(ks, 1); pb = (unsigned)DPP_ROR(kb, 1); KM2_COMBINE;
    ps = (unsigned)DPP_ROR(ks, 2); pb = (unsigned)DPP_ROR(kb, 2); KM2_COMBINE;
    ps = (unsigned)DPP_ROR(ks, 4); pb = (unsigned)DPP_ROR(kb, 4); KM2_COMBINE;
    ps = (unsigned)DPP_ROR(ks, 8); pb = (unsigned)DPP_ROR(kb, 8); KM2_COMBINE;
#if __has_builtin(__builtin_amdgcn_permlane16_swap)
    {
        uint32x2_t rs = __builtin_amdgcn_permlane16_swap(ks, ks, false, false);
        uint32x2_t rb = __builtin_amdgcn_permlane16_swap(kb, kb, false, false);
        ps = (lane & 16) ? rs[0] : rs[1]; pb = (lane & 16) ? rb[0] : rb[1];
    }
    KM2_COMBINE;
#else
    ps = (unsigned)__shfl_xor((int)ks, 16); pb = (unsigned)__shfl_xor((int)kb, 16); KM2_COMBINE;
#endif
#if __has_builtin(__builtin_amdgcn_permlane32_swap)
    {
        uint32x2_t rs = __builtin_amdgcn_permlane32_swap(ks, ks, false, false);
        uint32x2_t rb = __builtin_amdgcn_permlane32_swap(kb, kb, false, false);
        ps = (lane & 32) ? rs[0] : rs[1]; pb = (lane & 32) ? rb[0] : rb[1];
    }
    KM2_COMBINE;
#else
    ps = (unsigned)__shfl_xor((int)ks, 32); pb = (unsigned)__shfl_xor((int)kb, 32); KM2_COMBINE;
#endif
#undef KM2_COMBINE
}

// One block = one batch, 64 threads (1 wave). epsilon-scaling auction (min-cost form):
// row i bids on argmin_j (dist[i][j] + p[j]); bid raises price by (m2-m1)+eps.
// Jacobi parallel rounds while many rows free; wave-cooperative Gauss-Seidel for the tail.
// Final assignment within N*eps_f of optimal; sum uses exact distances.
__global__ __launch_bounds__(64, 1)
void lsap_kernel(const float* __restrict__ y_true, const float* __restrict__ y_pred,
                 float* __restrict__ batch_sums, float* __restrict__ out, int use_atomic) {
    __shared__ float dist[N * N];      // 64 KB, row-major
    __shared__ float ytl[N * DIM];     // 32 KB
    __shared__ float v_lds[N];         // column prices (mirror; registers are master)
    __shared__ unsigned bid[N];        // Jacobi bid box: (monokey(price) & ~127) | row
    __shared__ int rowcol[N];          // col assigned to row, -1 free (Jacobi bookkeeping)

    const int b = blockIdx.x;
    const int lane = threadIdx.x;
    const int ca = lane, cb = lane + 64;   // owned columns

    // ---- stage y_true[b] into LDS ----
    {
        const float4* yt4 = (const float4*)(y_true + (size_t)b * N * DIM);
        float4* ytl4 = (float4*)ytl;
        for (int k = lane; k < N * DIM / 4; k += 64) ytl4[k] = yt4[k];
    }
    // ---- y_pred rows ca, cb into registers ----
    float ypa[DIM], ypb[DIM];
    {
        const float4* pa4 = (const float4*)(y_pred + (size_t)b * N * DIM + (size_t)ca * DIM);
        const float4* pb4 = (const float4*)(y_pred + (size_t)b * N * DIM + (size_t)cb * DIM);
        #pragma unroll
        for (int k = 0; k < DIM / 4; ++k) {
            float4 v4 = pa4[k];
            ypa[4*k+0]=v4.x; ypa[4*k+1]=v4.y; ypa[4*k+2]=v4.z; ypa[4*k+3]=v4.w;
            float4 w4 = pb4[k];
            ypb[4*k+0]=w4.x; ypb[4*k+1]=w4.y; ypb[4*k+2]=w4.z; ypb[4*k+3]=w4.w;
        }
    }
    __syncthreads();

    // ---- Phase A: dist row-major + column minima ----
    float cmin_a = INFINITY, cmin_b = INFINITY;
    for (int i = 0; i < N; ++i) {
        const float4* yr = (const float4*)(ytl + i * DIM);
        float a0 = 0.f, a1 = 0.f;
        #pragma unroll
        for (int k = 0; k < DIM / 4; ++k) {
            float4 t4 = yr[k];
            float d;
            d = t4.x - ypa[4*k+0]; a0 = fmaf(d, d, a0);
            d = t4.y - ypa[4*k+1]; a0 = fmaf(d, d, a0);
            d = t4.z - ypa[4*k+2]; a0 = fmaf(d, d, a0);
            d = t4.w - ypa[4*k+3]; a0 = fmaf(d, d, a0);
            d = t4.x - ypb[4*k+0]; a1 = fmaf(d, d, a1);
            d = t4.y - ypb[4*k+1]; a1 = fmaf(d, d, a1);
            d = t4.z - ypb[4*k+2]; a1 = fmaf(d, d, a1);
            d = t4.w - ypb[4*k+3]; a1 = fmaf(d, d, a1);
        }
        float d0 = sqrtf(a0), d1 = sqrtf(a1);
        dist[i * N + ca] = d0;
        dist[i * N + cb] = d1;
        cmin_a = fminf(cmin_a, d0);
        cmin_b = fminf(cmin_b, d1);
    }

    // Price init: column-reduction analog (normalizes reduced costs to min 0 per col).
    float pva = -cmin_a, pvb = -cmin_b;    // register master
    int ow_a = -1, ow_b = -1;              // owning row per column (-1 free)
    v_lds[ca] = pva; v_lds[cb] = pvb;
    __syncthreads();                        // dist + prices visible

    int rounds = MAX_ROUNDS;
    int fa = 1, fb = 1;                    // rows lane / lane+64 free

    for (int sc = 0; sc < NSCALES; ++sc) {
        float eps = (sc == 0) ? 1.6f : (sc == 1) ? 0.4f : (sc == 2) ? 0.1f : 0.025f;
        __syncthreads();                   // drain pending GS writes from prior scale
        ow_a = -1; ow_b = -1;
        rowcol[lane] = -1; rowcol[lane + 64] = -1;
        fa = 1; fb = 1;
        __syncthreads();

        for (;;) {
            unsigned long long ba = __ballot(fa), bbm = __ballot(fb);
            int f = __popcll(ba) + __popcll(bbm);
            if (f == 0 || rounds <= 0) break;
            --rounds;

            if (f >= JACOBI_MIN_FREE) {
                // -------- Jacobi parallel bidding round --------
                bid[ca] = 0u; bid[cb] = 0u;
                __syncthreads();
                #pragma unroll
                for (int half = 0; half < 2; ++half) {
                    int act = half ? fb : fa;
                    int i = half ? (lane + 64) : lane;
                    if (act) {
                        const float* dr = dist + i * N;
                        float m1 = INFINITY, m2 = INFINITY; int j1 = 0;
                        #pragma unroll 4
                        for (int t = 0; t < N; ++t) {
                            int j = (t + lane) & (N - 1);     // rotated: conflict-free
                            float c = dr[j] + v_lds[j];
                            float mx = fmaxf(m1, c);
                            m2 = fminf(m2, mx);
                            if (c < m1) { m1 = c; j1 = j; }
                        }
                        float newp = v_lds[j1] + (m2 - m1) + eps;
                        unsigned pk = (monokey(newp) & ~127u) | (unsigned)i;
                        atomicMax(&bid[j1], pk);
                    }
                }
                __syncthreads();
                // resolve own columns (winner rows distinct; freed rows distinct)
                {
                    unsigned w0 = bid[ca];
                    if (w0) {
                        int wr = (int)(w0 & 127u);
                        float np = monoval(w0 & ~127u);
                        if (ow_a >= 0) rowcol[ow_a] = -1;
                        rowcol[wr] = ca;
                        ow_a = wr; pva = np; v_lds[ca] = np;
                    }
                    unsigned w1 = bid[cb];
                    if (w1) {
                        int wr = (int)(w1 & 127u);
                        float np = monoval(w1 & ~127u);
                        if (ow_b >= 0) rowcol[ow_b] = -1;
                        rowcol[wr] = cb;
                        ow_b = wr; pvb = np; v_lds[cb] = np;
                    }
                }
                __syncthreads();
                fa = (rowcol[lane] < 0) ? 1 : 0;
                fb = (rowcol[lane + 64] < 0) ? 1 : 0;
            } else {
                // -------- Gauss-Seidel wave-cooperative bid (one row) --------
                int i = (ba != 0ull) ? (int)(__ffsll(ba) - 1) : (64 + (int)(__ffsll(bbm) - 1));
                const float* dr = dist + i * N;
                float c0 = dr[ca] + pva;
                float c1 = dr[cb] + pvb;
                unsigned k0 = (monokey(c0) & ~0x7Fu) | (unsigned)lane;
                unsigned k1 = (monokey(c1) & ~0x7Fu) | 64u | (unsigned)lane;
                unsigned ks = umin_(k0, k1), kb2 = umax_(k0, k1);
                wave_kmin2(ks, kb2, lane);
                int s1 = rfl((int)ks), s2 = rfl((int)kb2);
                int w = s1 & 63, cbit = (s1 >> 6) & 1;
                float m1 = rl_f(cbit ? c1 : c0, w);
                float m2 = rl_f(((s2 >> 6) & 1) ? c1 : c0, s2 & 63);
                float vold = rl_f(cbit ? pvb : pva, w);
                int old = rl_i(cbit ? ow_b : ow_a, w);
                float newp = vold + (m2 - m1) + eps;
                int col = w + (cbit << 6);
                if (lane == w) {
                    if (cbit) { ow_b = i; pvb = newp; v_lds[cb] = newp; }
                    else      { ow_a = i; pva = newp; v_lds[ca] = newp; }
                    rowcol[i] = col;
                    if (old >= 0) rowcol[old] = -1;
                }
                if ((i & 63) == lane) { if (i < 64) fa = 0; else fb = 0; }
                if (old >= 0 && (old & 63) == lane) { if (old < 64) fa = 1; else fb = 1; }
                // no barrier: prices/owners live in registers; LDS mirrors consumed
                // only after the next scale's __syncthreads (f is non-increasing).
            }
        }
    }

    // ---- fallback completion (only if round cap hit): free rows -> cheapest unowned col ----
    for (int guard = 0; guard < N; ++guard) {
        unsigned long long ba = __ballot(fa), bbm = __ballot(fb);
        if (!(ba | bbm)) break;
        int i = (ba != 0ull) ? (int)(__ffsll(ba) - 1) : (64 + (int)(__ffsll(bbm) - 1));
        const float* dr = dist + i * N;
        float c0 = (ow_a < 0) ? dr[ca] : INFINITY;
        float c1 = (ow_b < 0) ? dr[cb] : INFINITY;
        unsigned k0 = (monokey(c0) & ~0x7Fu) | (unsigned)lane;
        unsigned k1 = (monokey(c1) & ~0x7Fu) | 64u | (unsigned)lane;
        unsigned kk = wave_kmin(umin_(k0, k1));
        int s = rfl((int)kk);
        int w = s & 63, cbit = (s >> 6) & 1;
        if (lane == w) { if (cbit) ow_b = i; else ow_a = i; }
        if ((i & 63) == lane) { if (i < 64) fa = 0; else fb = 0; }
    }

    // ---- matched sum (exact distances) ----
    float s = dist[ow_a * N + ca] + dist[ow_b * N + cb];
    #pragma unroll
    for (int m = 1; m < 64; m <<= 1) s += __shfl_xor(s, m);
    if (lane == 0) {
        if (use_atomic) atomicAdd(out, s * (1.0f / (float)BATCH));
        else batch_sums[b] = s;
    }
}

__global__ __launch_bounds__(64)
void reduce_kernel(const float* __restrict__ bs, float* __restrict__ out) {
    int tid = threadIdx.x;
    float v = bs[tid];
    #pragma unroll
    for (int m = 1; m < 64; m <<= 1) v += __shfl_xor(v, m);
    if (tid == 0) out[0] = v * (1.0f / (float)BATCH);
}

extern "C" void kernel_launch(void* const* d_in, const int* in_sizes, int n_in,
                              void* d_out, int out_size, void* d_ws, size_t ws_size,
                              hipStream_t stream) {
    const float* y_true = (const float*)d_in[0];
    const float* y_pred = (const float*)d_in[1];
    float* out = (float*)d_out;

    if (ws_size >= BATCH * sizeof(float)) {
        float* bs = (float*)d_ws;
        lsap_kernel<<<BATCH, 64, 0, stream>>>(y_true, y_pred, bs, out, 0);
        reduce_kernel<<<1, 64, 0, stream>>>(bs, out);
    } else {
        hipMemsetAsync(d_out, 0, sizeof(float), stream);
        lsap_kernel<<<BATCH, 64, 0, stream>>>(y_true, y_pred, nullptr, out, 1);
    }
}

// Round 7
// 592.410 us; speedup vs baseline: 1.1844x; 1.1097x over previous
//
#include <hip/hip_runtime.h>
#include <math.h>
#include <stdint.h>

#define BATCH 64
#define N 128
#define DIM 64
#define ARR_CAP 640

typedef unsigned uint32x2_t __attribute__((ext_vector_type(2)));

// branchless monotone float->uint (order-preserving incl. +-inf)
__device__ __forceinline__ unsigned monokey(float x) {
    unsigned b = __float_as_uint(x);
    return b ^ (unsigned)(((int)b >> 31) | (int)0x80000000u);
}

__device__ __forceinline__ unsigned umin_(unsigned a, unsigned b) { return a < b ? a : b; }
__device__ __forceinline__ unsigned umax_(unsigned a, unsigned b) { return a > b ? a : b; }
__device__ __forceinline__ int rfl(int v) { return __builtin_amdgcn_readfirstlane(v); }
__device__ __forceinline__ int rl_i(int v, int l) { return __builtin_amdgcn_readlane(v, l); }
__device__ __forceinline__ float rl_f(float v, int l) {
    return __int_as_float(__builtin_amdgcn_readlane(__float_as_int(v), l));
}

#define DPP_ROR(x, n) __builtin_amdgcn_update_dpp((int)(x), (int)(x), 0x120 + (n), 0xF, 0xF, false)

// full-wave min of packed keys; every lane gets the result. VALU-only.
__device__ __forceinline__ unsigned wave_kmin(unsigned k) {
    unsigned a = (unsigned)DPP_ROR(k, 1);
    unsigned b = (unsigned)DPP_ROR(k, 2);
    k = umin_(k, umin_(a, b));            // 0..2
    a = (unsigned)DPP_ROR(k, 3);
    b = (unsigned)DPP_ROR(k, 6);
    k = umin_(k, umin_(a, b));            // 0..8
    a = (unsigned)DPP_ROR(k, 9);
    k = umin_(k, a);                      // 0..15 (wrap overlap OK for min)
#if __has_builtin(__builtin_amdgcn_permlane16_swap)
    { uint32x2_t r = __builtin_amdgcn_permlane16_swap(k, k, false, false); k = umin_(r[0], r[1]); }
#else
    k = umin_(k, (unsigned)__shfl_xor((int)k, 16));
#endif
#if __has_builtin(__builtin_amdgcn_permlane32_swap)
    { uint32x2_t r = __builtin_amdgcn_permlane32_swap(k, k, false, false); k = umin_(r[0], r[1]); }
#else
    k = umin_(k, (unsigned)__shfl_xor((int)k, 32));
#endif
    return k;
}

// two smallest keys across the wave (disjoint-window rotate-reduce). ks<=kb kept.
__device__ __forceinline__ void wave_kmin2(unsigned& ks, unsigned& kb, int lane) {
    unsigned ps, pb;
#define KM2_COMBINE { unsigned ns = umin_(ks, ps); kb = umin_(umin_(kb, pb), umax_(ks, ps)); ks = ns; }
    ps = (unsigned)DPP_ROR(ks, 1); pb = (unsigned)DPP_ROR(kb, 1); KM2_COMBINE;
    ps = (unsigned)DPP_ROR(ks, 2); pb = (unsigned)DPP_ROR(kb, 2); KM2_COMBINE;
    ps = (unsigned)DPP_ROR(ks, 4); pb = (unsigned)DPP_ROR(kb, 4); KM2_COMBINE;
    ps = (unsigned)DPP_ROR(ks, 8); pb = (unsigned)DPP_ROR(kb, 8); KM2_COMBINE;
#if __has_builtin(__builtin_amdgcn_permlane16_swap)
    {
        uint32x2_t rs = __builtin_amdgcn_permlane16_swap(ks, ks, false, false);
        uint32x2_t rb = __builtin_amdgcn_permlane16_swap(kb, kb, false, false);
        ps = (lane & 16) ? rs[0] : rs[1]; pb = (lane & 16) ? rb[0] : rb[1];
    }
    KM2_COMBINE;
#else
    ps = (unsigned)__shfl_xor((int)ks, 16); pb = (unsigned)__shfl_xor((int)kb, 16); KM2_COMBINE;
#endif
#if __has_builtin(__builtin_amdgcn_permlane32_swap)
    {
        uint32x2_t rs = __builtin_amdgcn_permlane32_swap(ks, ks, false, false);
        uint32x2_t rb = __builtin_amdgcn_permlane32_swap(kb, kb, false, false);
        ps = (lane & 32) ? rs[0] : rs[1]; pb = (lane & 32) ? rb[0] : rb[1];
    }
    KM2_COMBINE;
#else
    ps = (unsigned)__shfl_xor((int)ks, 32); pb = (unsigned)__shfl_xor((int)kb, 32); KM2_COMBINE;
#endif
#undef KM2_COMBINE
}

// One block = one batch, 64 threads (1 wave). Lane owns 1-based columns ja=lane+1, jb=lane+65.
// Decision sequence identical to R4 (595us run); LDS dist-row reads prefetched so their
// ~120cy latency overlaps the readlane decode + dual-update chains.
__global__ __launch_bounds__(64, 1)
void lsap_kernel(const float* __restrict__ y_true, const float* __restrict__ y_pred,
                 float* __restrict__ batch_sums, float* __restrict__ out, int use_atomic) {
    __shared__ float dist[N * N];            // 64 KB; columns ca/cb read only by owner lane
    __shared__ float ytl[N * DIM];           // 32 KB
    __shared__ int unlist[N + ARR_CAP + 8];  // free-row queue

    const int b = blockIdx.x;
    const int lane = threadIdx.x;
    const int ca = lane, cb = lane + 64;
    const int ja = lane + 1, jb = lane + 65;

    // ---- stage y_true[b] into LDS ----
    {
        const float4* yt4 = (const float4*)(y_true + (size_t)b * N * DIM);
        float4* ytl4 = (float4*)ytl;
        for (int k = lane; k < N * DIM / 4; k += 64) ytl4[k] = yt4[k];
    }

    // ---- y_pred rows ca, cb into registers ----
    float ypa[DIM], ypb[DIM];
    {
        const float4* pa4 = (const float4*)(y_pred + (size_t)b * N * DIM + (size_t)ca * DIM);
        const float4* pb4 = (const float4*)(y_pred + (size_t)b * N * DIM + (size_t)cb * DIM);
        #pragma unroll
        for (int k = 0; k < DIM / 4; ++k) {
            float4 v4 = pa4[k];
            ypa[4*k+0]=v4.x; ypa[4*k+1]=v4.y; ypa[4*k+2]=v4.z; ypa[4*k+3]=v4.w;
            float4 w4 = pb4[k];
            ypb[4*k+0]=w4.x; ypb[4*k+1]=w4.y; ypb[4*k+2]=w4.z; ypb[4*k+3]=w4.w;
        }
    }
    __syncthreads();   // ytl visible

    // ---- Phase A: dist columns + column minima (v init) ----
    float va = INFINITY, vb = INFINITY;      // v[ja], v[jb]
    for (int i = 0; i < N; ++i) {
        const float4* yr = (const float4*)(ytl + i * DIM);
        float a0 = 0.f, a1 = 0.f;
        #pragma unroll
        for (int k = 0; k < DIM / 4; ++k) {
            float4 t4 = yr[k];
            float d;
            d = t4.x - ypa[4*k+0]; a0 = fmaf(d, d, a0);
            d = t4.y - ypa[4*k+1]; a0 = fmaf(d, d, a0);
            d = t4.z - ypa[4*k+2]; a0 = fmaf(d, d, a0);
            d = t4.w - ypa[4*k+3]; a0 = fmaf(d, d, a0);
            d = t4.x - ypb[4*k+0]; a1 = fmaf(d, d, a1);
            d = t4.y - ypb[4*k+1]; a1 = fmaf(d, d, a1);
            d = t4.z - ypb[4*k+2]; a1 = fmaf(d, d, a1);
            d = t4.w - ypb[4*k+3]; a1 = fmaf(d, d, a1);
        }
        float d0 = sqrtf(a0), d1 = sqrtf(a1);
        dist[i * N + ca] = d0;
        dist[i * N + cb] = d1;
        va = fminf(va, d0);
        vb = fminf(vb, d1);
    }

    // Column state in registers.
    int   pa = 0, pb = 0;          // assigned row (1-based; 0=free)
    float upa = 0.f, upb = 0.f;    // u[p[j]]
    float ura = 0.f, urb = 0.f;    // u_row for rows lane / lane+64
    int   waya = 0, wayb = 0;

    // ---- Phase B: row minima (kmin2) + greedy assignment with reduction transfer ----
    // Decisions identical to R4; next row's raw dist prefetched (value-neutral).
    int nun = 0;
    float pd0 = dist[ca], pd1 = dist[cb];
    for (int r = 0; r < N; ++r) {
        float c0 = pd0 - va, c1 = pd1 - vb;
        if (r + 1 < N) { pd0 = dist[(r+1) * N + ca]; pd1 = dist[(r+1) * N + cb]; }
        unsigned k0 = (monokey(c0) & ~0x7Fu) | (unsigned)lane;
        unsigned k1 = (monokey(c1) & ~0x7Fu) | 64u | (unsigned)lane;
        unsigned ks = umin_(k0, k1), kb2 = umax_(k0, k1);
        wave_kmin2(ks, kb2, lane);
        int s1 = rfl((int)ks);
        int s2 = rfl((int)kb2);
        int w1 = s1 & 63, cb1 = (s1 >> 6) & 1;
        float u1 = rl_f(cb1 ? c1 : c0, w1);
        float u2 = rl_f(((s2 >> 6) & 1) ? c1 : c0, s2 & 63);
        int j1 = 1 + w1 + (cb1 << 6);
        int pj1 = rl_i(cb1 ? pb : pa, w1);
        if (pj1 == 0) {
            float dd = u2 - u1;              // reduction transfer
            if (ja == j1) { pa = r + 1; upa = u2; va -= dd; }
            if (jb == j1) { pb = r + 1; upb = u2; vb -= dd; }
            if ((r & 63) == lane) { if (r < 64) ura = u2; else urb = u2; }
        } else {
            unlist[nun] = r;
            ++nun;
            if ((r & 63) == lane) { if (r < 64) ura = u1; else urb = u1; }
        }
    }

    // ---- Augmenting row reduction (LAPJV), R4 order (pending=immediate on transfer,
    //      append-to-back otherwise); displaced-row dists speculatively prefetched.
    int qk = 0, nf = nun;
    {
        int ops = 0;
        int icur = -1;
        float d0c = 0.f, d1c = 0.f;
        int qi = -1; float qd0 = 0.f, qd1 = 0.f;
        if (nun > 0) {
            icur = rfl(unlist[0]); qk = 1;
            d0c = dist[icur * N + ca]; d1c = dist[icur * N + cb];
            if (qk < nf) { qi = rfl(unlist[qk]); qd0 = dist[qi * N + ca]; qd1 = dist[qi * N + cb]; }
        }
        while (icur >= 0 && ops < ARR_CAP) {
            ++ops;
            float c0 = d0c - va, c1 = d1c - vb;
            unsigned k0 = (monokey(c0) & ~0x7Fu) | (unsigned)lane;
            unsigned k1 = (monokey(c1) & ~0x7Fu) | 64u | (unsigned)lane;
            unsigned ks = umin_(k0, k1), kb2 = umax_(k0, k1);
            wave_kmin2(ks, kb2, lane);
            int s1 = rfl((int)ks);
            int s2 = rfl((int)kb2);
            int w1 = s1 & 63, cb1 = (s1 >> 6) & 1;
            int w2 = s2 & 63, cb2 = (s2 >> 6) & 1;
            int pj1 = rl_i(cb1 ? pb : pa, w1);
            int pj2 = rl_i(cb2 ? pb : pa, w2);
            // speculative prefetch of both possible displaced rows (overlaps decode below)
            float sa0 = 0.f, sa1 = 0.f, sb0 = 0.f, sb1 = 0.f;
            if (pj1) { sa0 = dist[(pj1 - 1) * N + ca]; sa1 = dist[(pj1 - 1) * N + cb]; }
            if (pj2) { sb0 = dist[(pj2 - 1) * N + ca]; sb1 = dist[(pj2 - 1) * N + cb]; }
            float u1 = rl_f(cb1 ? c1 : c0, w1);
            float u2 = rl_f(cb2 ? c1 : c0, w2);
            int j1 = 1 + w1 + (cb1 << 6);
            int j2 = 1 + w2 + (cb2 << 6);
            bool transfer = (u1 < u2);       // exact compare (R4 semantics)
            int jt, it0;
            if (transfer) {
                float dd = u2 - u1;
                if (ja == j1) va -= dd;
                if (jb == j1) vb -= dd;
                jt = j1; it0 = pj1;
            } else if (pj1 > 0) { jt = j2; it0 = pj2; }
            else { jt = j1; it0 = 0; }

            if (ja == jt) { pa = icur + 1; upa = u2; }
            if (jb == jt) { pb = icur + 1; upb = u2; }
            if ((icur & 63) == lane) { if (icur < 64) ura = u2; else urb = u2; }

            if (transfer && it0 > 0) {
                icur = it0 - 1; d0c = sa0; d1c = sa1;   // pending: reprocess displaced now
            } else {
                if (!transfer && pj1 > 0) { unlist[nf] = it0 - 1; ++nf; }  // append to back
                if (qk < nf) {
                    if (qi < 0) { icur = it0 - 1; d0c = sb0; d1c = sb1; }  // front == just-appended
                    else        { icur = qi;      d0c = qd0; d1c = qd1; }
                    ++qk;
                    if (qk < nf) {
                        qi = rfl(unlist[qk]);
                        qd0 = dist[qi * N + ca]; qd1 = dist[qi * N + cb];
                    } else qi = -1;
                } else icur = -1;
            }
        }
        if (icur >= 0) { --qk; unlist[qk] = icur; }   // push back unprocessed row
    }

    // ---- Dijkstra augmenting phases for remaining free rows ----
    for (int t = qk; t < nf; ++t) {
        int r = rfl(unlist[t]);
        float d0 = dist[r * N + ca], d1 = dist[r * N + cb];   // issue early
        float u_i = rl_f((r >= 64) ? urb : ura, r & 63);
        float mina = INFINITY, minb = INFINITY;
        int useda = 0, usedb = 0;
        waya = 0; wayb = 0;
        float uacca = 0.f, uaccb = 0.f;
        float u_acc_i = u_i;
        float u0c = u_i;
        int j0 = 0;

        for (int it = 0; it < 2 * N; ++it) {
            if (ja == j0) useda = 1;
            if (jb == j0) usedb = 1;
            if (!useda) { float cur = d0 - u0c - va; if (cur < mina) { mina = cur; waya = j0; } }
            if (!usedb) { float cur = d1 - u0c - vb; if (cur < minb) { minb = cur; wayb = j0; } }

            float fa_ = useda ? INFINITY : mina;
            float fb_ = usedb ? INFINITY : minb;
            // key: [31:15] value, [14:7] p (0=free col), [6] colbit, [5:0] lane
            unsigned kA = (monokey(fa_) & 0xFFFF8000u) | ((unsigned)pa << 7) | (unsigned)lane;
            unsigned kB = (monokey(fb_) & 0xFFFF8000u) | ((unsigned)pb << 7) | 64u | (unsigned)lane;
            unsigned kk = wave_kmin(umin_(kA, kB));
            int s = rfl((int)kk);
            int i1 = (s >> 7) & 0xFF;

            // issue next dist-row read immediately (i1 from key bits, SALU-only path)
            float nd0 = 0.f, nd1 = 0.f;
            if (i1) { nd0 = dist[(i1 - 1) * N + ca]; nd1 = dist[(i1 - 1) * N + cb]; }

            int w = s & 63, cbw = (s >> 6) & 1;
            float delta = rl_f(cbw ? fb_ : fa_, w);      // exact; overlaps LDS wait
            float u1v = rl_f(cbw ? upb : upa, w);

            if (useda) { va -= delta; uacca += delta; } else { mina -= delta; }
            if (usedb) { vb -= delta; uaccb += delta; } else { minb -= delta; }
            u_acc_i += delta;

            j0 = 1 + w + (cbw << 6);
            if (i1 == 0) break;
            u0c = u1v; d0 = nd0; d1 = nd1;
        }

        if (useda) upa += uacca;
        if (usedb) upb += uaccb;

        // ---- augment: register readlane chase (uniform) ----
        int jj = j0;
        for (int hop = 0; hop < N + 1; ++hop) {
            int wj = (jj - 1) & 63;
            int sbj = (jj > 64) ? 1 : 0;
            int jp = rl_i(sbj ? wayb : waya, wj);
            int np; float nu;
            if (jp == 0) { np = r + 1; nu = u_acc_i; }
            else {
                int wp = (jp - 1) & 63;
                int sbp = (jp > 64) ? 1 : 0;
                np = rl_i(sbp ? pb : pa, wp);
                nu = rl_f(sbp ? upb : upa, wp);
            }
            if (ja == jj) { pa = np; upa = nu; }
            if (jb == jj) { pb = np; upb = nu; }
            if (jp == 0) break;
            jj = jp;
        }
    }

    // ---- matched sum ----
    float s = dist[(pa - 1) * N + ca] + dist[(pb - 1) * N + cb];
    #pragma unroll
    for (int m = 1; m < 64; m <<= 1) s += __shfl_xor(s, m);
    if (lane == 0) {
        if (use_atomic) atomicAdd(out, s * (1.0f / (float)BATCH));
        else batch_sums[b] = s;
    }
}

__global__ __launch_bounds__(64)
void reduce_kernel(const float* __restrict__ bs, float* __restrict__ out) {
    int tid = threadIdx.x;
    float v = bs[tid];
    #pragma unroll
    for (int m = 1; m < 64; m <<= 1) v += __shfl_xor(v, m);
    if (tid == 0) out[0] = v * (1.0f / (float)BATCH);
}

extern "C" void kernel_launch(void* const* d_in, const int* in_sizes, int n_in,
                              void* d_out, int out_size, void* d_ws, size_t ws_size,
                              hipStream_t stream) {
    const float* y_true = (const float*)d_in[0];
    const float* y_pred = (const float*)d_in[1];
    float* out = (float*)d_out;

    if (ws_size >= BATCH * sizeof(float)) {
        float* bs = (float*)d_ws;
        lsap_kernel<<<BATCH, 64, 0, stream>>>(y_true, y_pred, bs, out, 0);
        reduce_kernel<<<1, 64, 0, stream>>>(bs, out);
    } else {
        hipMemsetAsync(d_out, 0, sizeof(float), stream);
        lsap_kernel<<<BATCH, 64, 0, stream>>>(y_true, y_pred, nullptr, out, 1);
    }
}